// Round 10
// baseline (184.167 us; speedup 1.0000x reference)
//
#include <hip/hip_runtime.h>
#include <hip/hip_bf16.h>
#include <hip/hip_fp16.h>

// Problem constants (B=8, T=4096, Din=Dout=256, WINDOW=2)
#define BDIM 8
#define TDIM 4096
#define DDIM 256
#define MDIM (BDIM * TDIM)      // 32768
#define NCHUNK 256              // chunks along T for the parallel scan
#define LCHUNK (TDIM / NCHUNK)  // 16

typedef _Float16 f16x8 __attribute__((ext_vector_type(8)));
typedef _Float16 f16x4 __attribute__((ext_vector_type(4)));
typedef float f32x4 __attribute__((ext_vector_type(4)));

__device__ __forceinline__ float sigmoid_(float x) {
    return 1.0f / (1.0f + __expf(-x));
}
__device__ __forceinline__ float tanh_(float x) {
    return 2.0f / (1.0f + __expf(-2.0f * x)) - 1.0f;
}

#define GLOAD_LDS16(g, l)                                                    \
    __builtin_amdgcn_global_load_lds(                                        \
        (const __attribute__((address_space(1))) void*)(g),                  \
        (__attribute__((address_space(3))) void*)(l), 16, 0, 0)

// ---------------------------------------------------------------------------
// Fused prep: blocks [0,1536) convert W, blocks [1536,9736) convert x.
// ---------------------------------------------------------------------------
__global__ __launch_bounds__(256) void prep(
    const float* __restrict__ x, _Float16* __restrict__ xpad,
    const float* __restrict__ Wz, const float* __restrict__ Wf,
    const float* __restrict__ Wo, _Float16* __restrict__ Wt) {
    const int bx = blockIdx.x;
    if (bx < 1536) {  // convert_w: 1536*256 = 3*2*256*256 threads
        const int idx = bx * 256 + threadIdx.x;
        const int n = idx & 255;
        const int kin = (idx >> 8) & 255;
        const int w = (idx >> 16) & 1;
        const int g = idx >> 17;
        const float* W = (g == 0) ? Wz : (g == 1) ? Wf : Wo;
        const float v = W[(size_t)w * 65536 + (size_t)kin * 256 + n];
        Wt[((size_t)g * 256 + n) * 512 + w * 256 + kin] = (_Float16)v;
        return;
    }
    const int bxx = bx - 1536;        // 8200 blocks: 1025 per batch
    const int b = bxx / 1025;
    const int tb = bxx - b * 1025;
    const int tp = tb * 4 + (threadIdx.x >> 6);  // padded row 0..4096
    const int q = threadIdx.x & 63;
    if (tp > TDIM) return;
    float4 v = make_float4(0.f, 0.f, 0.f, 0.f);
    if (tp > 0)
        v = *(const float4*)(x + ((size_t)b * TDIM + tp - 1) * DDIM + q * 4);
    f16x4 h;
    h[0] = (_Float16)v.x; h[1] = (_Float16)v.y;
    h[2] = (_Float16)v.z; h[3] = (_Float16)v.w;
    *(f16x4*)(xpad + ((size_t)b * (TDIM + 1) + tp) * DDIM + q * 4) = h;
}

// ---------------------------------------------------------------------------
// MFMA GEMM, BK=64 two-phase K-tiles -- R7-verified config (42.2 us, best of
// six structural variants; reverted here after R9's 8-wave regression).
// ---------------------------------------------------------------------------
__global__ __launch_bounds__(256, 2) void gates_mfma(
    const _Float16* __restrict__ xpad, const _Float16* __restrict__ Wt,
    const float* __restrict__ bz, const float* __restrict__ bfv,
    const float* __restrict__ bo,
    _Float16* __restrict__ zbuf, _Float16* __restrict__ fbuf,
    _Float16* __restrict__ obuf) {
    const int hw = blockIdx.x;
    const int logical = (hw & 7) * 192 + (hw >> 3);
    const int mblk = logical / 6;
    const int rem = logical - mblk * 6;   // (n,gate) innermost
    const int gate = rem % 3;
    const int nblk = rem / 3;
    const int m0 = mblk * 128;
    const int n0 = nblk * 128;

    const int tid = threadIdx.x;
    const int lane = tid & 63;
    const int wave = tid >> 6;
    const int wr = wave >> 1;
    const int wc = wave & 1;

    __shared__ __align__(16) char smem[65536];

    const int s = wave * 64 + lane;
    const int r1 = s >> 3;
    const int kc = (((s & 7) ^ ((s >> 3) & 7))) * 8;

    const int b = m0 >> 12;
    const int t0 = m0 & (TDIM - 1);

    const _Float16* srcA =
        xpad + ((size_t)b * (TDIM + 1) + t0 + r1) * DDIM + kc;
    const _Float16* srcB = Wt + ((size_t)gate * 256 + n0 + r1) * 512 + kc;

#define STAGE_(slot, kt)                                                     \
    {                                                                        \
        char* dA = smem + (slot) * 32768 + wave * 1024;                      \
        char* dB = smem + (slot) * 32768 + 16384 + wave * 1024;              \
        GLOAD_LDS16(srcA + (kt) * 64, dA);                                   \
        GLOAD_LDS16(srcA + (kt) * 64 + 32 * DDIM, dA + 4096);                \
        GLOAD_LDS16(srcA + (kt) * 64 + 64 * DDIM, dA + 8192);                \
        GLOAD_LDS16(srcA + (kt) * 64 + 96 * DDIM, dA + 12288);               \
        GLOAD_LDS16(srcB + (kt) * 64, dB);                                   \
        GLOAD_LDS16(srcB + (kt) * 64 + 32 * 512, dB + 4096);                 \
        GLOAD_LDS16(srcB + (kt) * 64 + 64 * 512, dB + 8192);                 \
        GLOAD_LDS16(srcB + (kt) * 64 + 96 * 512, dB + 12288);               \
    }

    f32x4 acc[4][4] = {};
    const int am = lane & 15;
    const int c0 = (((lane >> 4) ^ (lane & 7))) * 8;
    const int c1 = (((4 + (lane >> 4)) ^ (lane & 7))) * 8;

    STAGE_(0, 0);

#pragma unroll
    for (int t = 0; t < 8; ++t) {
        asm volatile("s_waitcnt vmcnt(0)" ::: "memory");
        __builtin_amdgcn_s_barrier();
        __builtin_amdgcn_sched_barrier(0);
        if (t < 7) STAGE_((t + 1) & 1, t + 1);

        const _Float16* Ab = (const _Float16*)(smem + (t & 1) * 32768);
        const _Float16* Bb = Ab + 8192;  // halves

        f16x8 a0[4], b0[4], a1[4], b1[4];
#pragma unroll
        for (int i = 0; i < 4; ++i)
            a0[i] = *(const f16x8*)(Ab + (wr * 64 + i * 16 + am) * 64 + c0);
#pragma unroll
        for (int j = 0; j < 4; ++j)
            b0[j] = *(const f16x8*)(Bb + (wc * 64 + j * 16 + am) * 64 + c0);
        __builtin_amdgcn_sched_barrier(0);
#pragma unroll
        for (int i = 0; i < 4; ++i)
            a1[i] = *(const f16x8*)(Ab + (wr * 64 + i * 16 + am) * 64 + c1);
#pragma unroll
        for (int j = 0; j < 4; ++j)
            b1[j] = *(const f16x8*)(Bb + (wc * 64 + j * 16 + am) * 64 + c1);

        asm volatile("s_waitcnt lgkmcnt(8)" ::: "memory");
        __builtin_amdgcn_sched_barrier(0);
        __builtin_amdgcn_s_setprio(1);
#pragma unroll
        for (int i = 0; i < 4; ++i)
#pragma unroll
            for (int j = 0; j < 4; ++j)
                acc[i][j] = __builtin_amdgcn_mfma_f32_16x16x32_f16(
                    b0[j], a0[i], acc[i][j], 0, 0, 0);
        __builtin_amdgcn_s_setprio(0);
        asm volatile("s_waitcnt lgkmcnt(0)" ::: "memory");
        __builtin_amdgcn_sched_barrier(0);
        __builtin_amdgcn_s_setprio(1);
#pragma unroll
        for (int i = 0; i < 4; ++i)
#pragma unroll
            for (int j = 0; j < 4; ++j)
                acc[i][j] = __builtin_amdgcn_mfma_f32_16x16x32_f16(
                    b1[j], a1[i], acc[i][j], 0, 0, 0);
        __builtin_amdgcn_s_setprio(0);
    }
#undef STAGE_

    const float* bias = (gate == 0) ? bz : (gate == 1) ? bfv : bo;
    _Float16* outp = (gate == 0) ? zbuf : (gate == 1) ? fbuf : obuf;
    const int nq = (lane >> 4) * 4;
#pragma unroll
    for (int i = 0; i < 4; ++i) {
        const size_t gm = (size_t)(m0 + wr * 64 + i * 16 + am);
#pragma unroll
        for (int j = 0; j < 4; ++j) {
            const int gc = n0 + wc * 64 + j * 16 + nq;
            const float4 b4 = *(const float4*)(bias + gc);
            f32x4 v = acc[i][j];
            f16x4 h;
            if (gate == 0) {
                h[0] = (_Float16)tanh_(v[0] + b4.x);
                h[1] = (_Float16)tanh_(v[1] + b4.y);
                h[2] = (_Float16)tanh_(v[2] + b4.z);
                h[3] = (_Float16)tanh_(v[3] + b4.w);
            } else {
                h[0] = (_Float16)sigmoid_(v[0] + b4.x);
                h[1] = (_Float16)sigmoid_(v[1] + b4.y);
                h[2] = (_Float16)sigmoid_(v[2] + b4.z);
                h[3] = (_Float16)sigmoid_(v[3] + b4.w);
            }
            *(f16x4*)(outp + gm * DDIM + gc) = h;
        }
    }
}

// ---------------------------------------------------------------------------
// Scan pass 1 + fused carry scan (tail-block pattern).
// Per-chunk aggregates as before (4 ch/thread, 512 blocks; block bx serves
// batch b = bx>>6).  After a block's agg stores complete, thread 0 does a
// release-increment of cnt[b]; the LAST of the 64 blocks of that batch
// (old==63) proceeds to run the 256-thread carry scan for batch b.
// SPIN-FREE: non-last blocks exit; the winner depends only on FINISHED
// blocks (ACQ_REL agent-scope atomic orders the agg stores) -- no
// dispatch-order assumption (G16-safe, unlike R8's lookback).
// ---------------------------------------------------------------------------
__global__ __launch_bounds__(256) void scan_pass1(
    const _Float16* __restrict__ zbuf, const _Float16* __restrict__ fbuf,
    float* __restrict__ aggA, float* __restrict__ aggB,
    float* __restrict__ carry, int* __restrict__ cnt) {
    const int idx = blockIdx.x * 256 + threadIdx.x;  // < B*NCHUNK*64 = 131072
    const int d4 = idx & 63;
    const int chunk = (idx >> 6) & (NCHUNK - 1);
    const int b = idx >> 14;  // uniform per block (bx>>6)

    const size_t row0 = (size_t)b * TDIM + (size_t)chunk * LCHUNK;
    const int2* zp = (const int2*)zbuf + row0 * 64 + d4;
    const int2* fp = (const int2*)fbuf + row0 * 64 + d4;

    float A[4], c[4];
#pragma unroll
    for (int e = 0; e < 4; ++e) { A[e] = 1.0f; c[e] = 0.0f; }

    for (int i = 0; i < LCHUNK; ++i) {
        int2 fv = *fp;
        int2 zv = *zp;
        const _Float16* fh = (const _Float16*)&fv;
        const _Float16* zh = (const _Float16*)&zv;
#pragma unroll
        for (int e = 0; e < 4; ++e) {
            const float f = (float)fh[e];
            const float z = (float)zh[e];
            A[e] *= f;
            c[e] = f * c[e] + (1.0f - f) * z;
        }
        fp += 64;
        zp += 64;
    }
    ((float4*)aggA)[idx] = make_float4(A[0], A[1], A[2], A[3]);
    ((float4*)aggB)[idx] = make_float4(c[0], c[1], c[2], c[3]);

    // --- tail-block carry scan -------------------------------------------
    __shared__ int last_s;
    __syncthreads();  // all agg stores of this block issued
    if (threadIdx.x == 0) {
        __threadfence();  // make this block's agg stores visible
        const int old = __hip_atomic_fetch_add(&cnt[b], 1, __ATOMIC_ACQ_REL,
                                               __HIP_MEMORY_SCOPE_AGENT);
        last_s = (old == 63);  // 64 blocks per batch
    }
    __syncthreads();
    if (!last_s) return;

    // Winner: all 64 blocks of batch b finished (their stores ordered
    // before their release-increments).  Run batch-b carry scan: one
    // thread per d, 256 chunks serial, unroll-16 batched loads.
    const int d = threadIdx.x;  // 0..255
    const size_t base = (size_t)b * NCHUNK * 256 + d;
    float cc = 0.0f;
    for (int ch0 = 0; ch0 < NCHUNK; ch0 += 16) {
        float Ax[16], Bx[16];
#pragma unroll
        for (int u = 0; u < 16; ++u) {
            const size_t p = base + (size_t)(ch0 + u) * 256;
            Ax[u] = aggA[p];
            Bx[u] = aggB[p];
        }
#pragma unroll
        for (int u = 0; u < 16; ++u) {
            const size_t p = base + (size_t)(ch0 + u) * 256;
            carry[p] = cc;
            cc = Ax[u] * cc + Bx[u];
        }
    }
}

// ---------------------------------------------------------------------------
// Scan pass 2: replay chunk with true carry; h = o*c -> fp32 out.
// ---------------------------------------------------------------------------
__global__ __launch_bounds__(256) void scan_pass2(
    const _Float16* __restrict__ zbuf, const _Float16* __restrict__ fbuf,
    const _Float16* __restrict__ obuf, const float* __restrict__ carry,
    float* __restrict__ out) {
    const int idx = blockIdx.x * 256 + threadIdx.x;  // < 131072
    const int d4 = idx & 63;
    const int chunk = (idx >> 6) & (NCHUNK - 1);
    const int b = idx >> 14;

    float c[4];
    const float4 c0 = ((const float4*)carry)[idx];
    c[0] = c0.x; c[1] = c0.y; c[2] = c0.z; c[3] = c0.w;

    const size_t row0 = (size_t)b * TDIM + (size_t)chunk * LCHUNK;
    const int2* zp = (const int2*)zbuf + row0 * 64 + d4;
    const int2* fp = (const int2*)fbuf + row0 * 64 + d4;
    const int2* op = (const int2*)obuf + row0 * 64 + d4;
    float4* hp = (float4*)out + row0 * 64 + d4;

    for (int i = 0; i < LCHUNK; ++i) {
        int2 fv = *fp;
        int2 zv = *zp;
        int2 ov = *op;
        const _Float16* fh = (const _Float16*)&fv;
        const _Float16* zh = (const _Float16*)&zv;
        const _Float16* oh = (const _Float16*)&ov;
        float h[4];
#pragma unroll
        for (int e = 0; e < 4; ++e) {
            const float f = (float)fh[e];
            const float z = (float)zh[e];
            c[e] = f * c[e] + (1.0f - f) * z;
            h[e] = (float)oh[e] * c[e];
        }
        *hp = make_float4(h[0], h[1], h[2], h[3]);
        fp += 64;
        zp += 64;
        op += 64;
        hp += 64;
    }
}

extern "C" void kernel_launch(void* const* d_in, const int* in_sizes, int n_in,
                              void* d_out, int out_size, void* d_ws,
                              size_t ws_size, hipStream_t stream) {
    const float* x = (const float*)d_in[0];
    const float* Wz = (const float*)d_in[1];
    const float* Wf = (const float*)d_in[2];
    const float* Wo = (const float*)d_in[3];
    const float* bz = (const float*)d_in[4];
    const float* bfv = (const float*)d_in[5];
    const float* bo = (const float*)d_in[6];
    float* out = (float*)d_out;

    // Workspace (bytes): xpad 16.78M | Wt 0.79M | z 16.78M | f 16.78M |
    // o 16.78M | aggA 2M | aggB 2M | carry 2M | cnt 32B
    char* p = (char*)d_ws;
    _Float16* xpad = (_Float16*)p;  p += (size_t)BDIM * (TDIM + 1) * DDIM * 2;
    _Float16* Wt = (_Float16*)p;    p += (size_t)3 * 256 * 512 * 2;
    _Float16* zbuf = (_Float16*)p;  p += (size_t)MDIM * DDIM * 2;
    _Float16* fbuf = (_Float16*)p;  p += (size_t)MDIM * DDIM * 2;
    _Float16* obuf = (_Float16*)p;  p += (size_t)MDIM * DDIM * 2;
    float* aggA = (float*)p;        p += (size_t)BDIM * NCHUNK * DDIM * 4;
    float* aggB = (float*)p;        p += (size_t)BDIM * NCHUNK * DDIM * 4;
    float* carry = (float*)p;       p += (size_t)BDIM * NCHUNK * DDIM * 4;
    int* cnt = (int*)p;             p += 256;

    hipMemsetAsync(cnt, 0, 256, stream);

    prep<<<1536 + 1025 * BDIM, 256, 0, stream>>>(x, xpad, Wz, Wf, Wo, Wt);

    gates_mfma<<<MDIM / 128 * (DDIM / 128) * 3, 256, 0, stream>>>(
        xpad, Wt, bz, bfv, bo, zbuf, fbuf, obuf);

    scan_pass1<<<(BDIM * NCHUNK * 64) / 256, 256, 0, stream>>>(
        zbuf, fbuf, aggA, aggB, carry, cnt);
    scan_pass2<<<(BDIM * NCHUNK * 64) / 256, 256, 0, stream>>>(zbuf, fbuf,
                                                               obuf, carry, out);
}

// Round 11
// 161.502 us; speedup vs baseline: 1.1403x; 1.1403x over previous
//
#include <hip/hip_runtime.h>
#include <hip/hip_bf16.h>
#include <hip/hip_fp16.h>

// Problem constants (B=8, T=4096, Din=Dout=256, WINDOW=2)
#define BDIM 8
#define TDIM 4096
#define DDIM 256
#define MDIM (BDIM * TDIM)      // 32768
#define NCHUNK 256              // chunks along T for the parallel scan
#define LCHUNK (TDIM / NCHUNK)  // 16

typedef _Float16 f16x8 __attribute__((ext_vector_type(8)));
typedef _Float16 f16x4 __attribute__((ext_vector_type(4)));
typedef float f32x4 __attribute__((ext_vector_type(4)));

__device__ __forceinline__ float sigmoid_(float x) {
    return 1.0f / (1.0f + __expf(-x));
}
__device__ __forceinline__ float tanh_(float x) {
    return 2.0f / (1.0f + __expf(-2.0f * x)) - 1.0f;
}

#define GLOAD_LDS16(g, l)                                                    \
    __builtin_amdgcn_global_load_lds(                                        \
        (const __attribute__((address_space(1))) void*)(g),                  \
        (__attribute__((address_space(3))) void*)(l), 16, 0, 0)

// ---------------------------------------------------------------------------
// Fused prep: blocks [0,1536) convert W, blocks [1536,9736) convert x.
// ---------------------------------------------------------------------------
__global__ __launch_bounds__(256) void prep(
    const float* __restrict__ x, _Float16* __restrict__ xpad,
    const float* __restrict__ Wz, const float* __restrict__ Wf,
    const float* __restrict__ Wo, _Float16* __restrict__ Wt) {
    const int bx = blockIdx.x;
    if (bx < 1536) {  // convert_w: 1536*256 = 3*2*256*256 threads
        const int idx = bx * 256 + threadIdx.x;
        const int n = idx & 255;
        const int kin = (idx >> 8) & 255;
        const int w = (idx >> 16) & 1;
        const int g = idx >> 17;
        const float* W = (g == 0) ? Wz : (g == 1) ? Wf : Wo;
        const float v = W[(size_t)w * 65536 + (size_t)kin * 256 + n];
        Wt[((size_t)g * 256 + n) * 512 + w * 256 + kin] = (_Float16)v;
        return;
    }
    const int bxx = bx - 1536;        // 8200 blocks: 1025 per batch
    const int b = bxx / 1025;
    const int tb = bxx - b * 1025;
    const int tp = tb * 4 + (threadIdx.x >> 6);  // padded row 0..4096
    const int q = threadIdx.x & 63;
    if (tp > TDIM) return;
    float4 v = make_float4(0.f, 0.f, 0.f, 0.f);
    if (tp > 0)
        v = *(const float4*)(x + ((size_t)b * TDIM + tp - 1) * DDIM + q * 4);
    f16x4 h;
    h[0] = (_Float16)v.x; h[1] = (_Float16)v.y;
    h[2] = (_Float16)v.z; h[3] = (_Float16)v.w;
    *(f16x4*)(xpad + ((size_t)b * (TDIM + 1) + tp) * DDIM + q * 4) = h;
}

// ---------------------------------------------------------------------------
// MFMA GEMM, BK=64 two-phase K-tiles -- R7-verified config (42.2 us).
// ---------------------------------------------------------------------------
__global__ __launch_bounds__(256, 2) void gates_mfma(
    const _Float16* __restrict__ xpad, const _Float16* __restrict__ Wt,
    const float* __restrict__ bz, const float* __restrict__ bfv,
    const float* __restrict__ bo,
    _Float16* __restrict__ zbuf, _Float16* __restrict__ fbuf,
    _Float16* __restrict__ obuf) {
    const int hw = blockIdx.x;
    const int logical = (hw & 7) * 192 + (hw >> 3);
    const int mblk = logical / 6;
    const int rem = logical - mblk * 6;   // (n,gate) innermost
    const int gate = rem % 3;
    const int nblk = rem / 3;
    const int m0 = mblk * 128;
    const int n0 = nblk * 128;

    const int tid = threadIdx.x;
    const int lane = tid & 63;
    const int wave = tid >> 6;
    const int wr = wave >> 1;
    const int wc = wave & 1;

    __shared__ __align__(16) char smem[65536];

    const int s = wave * 64 + lane;
    const int r1 = s >> 3;
    const int kc = (((s & 7) ^ ((s >> 3) & 7))) * 8;

    const int b = m0 >> 12;
    const int t0 = m0 & (TDIM - 1);

    const _Float16* srcA =
        xpad + ((size_t)b * (TDIM + 1) + t0 + r1) * DDIM + kc;
    const _Float16* srcB = Wt + ((size_t)gate * 256 + n0 + r1) * 512 + kc;

#define STAGE_(slot, kt)                                                     \
    {                                                                        \
        char* dA = smem + (slot) * 32768 + wave * 1024;                      \
        char* dB = smem + (slot) * 32768 + 16384 + wave * 1024;              \
        GLOAD_LDS16(srcA + (kt) * 64, dA);                                   \
        GLOAD_LDS16(srcA + (kt) * 64 + 32 * DDIM, dA + 4096);                \
        GLOAD_LDS16(srcA + (kt) * 64 + 64 * DDIM, dA + 8192);                \
        GLOAD_LDS16(srcA + (kt) * 64 + 96 * DDIM, dA + 12288);               \
        GLOAD_LDS16(srcB + (kt) * 64, dB);                                   \
        GLOAD_LDS16(srcB + (kt) * 64 + 32 * 512, dB + 4096);                 \
        GLOAD_LDS16(srcB + (kt) * 64 + 64 * 512, dB + 8192);                 \
        GLOAD_LDS16(srcB + (kt) * 64 + 96 * 512, dB + 12288);               \
    }

    f32x4 acc[4][4] = {};
    const int am = lane & 15;
    const int c0 = (((lane >> 4) ^ (lane & 7))) * 8;
    const int c1 = (((4 + (lane >> 4)) ^ (lane & 7))) * 8;

    STAGE_(0, 0);

#pragma unroll
    for (int t = 0; t < 8; ++t) {
        asm volatile("s_waitcnt vmcnt(0)" ::: "memory");
        __builtin_amdgcn_s_barrier();
        __builtin_amdgcn_sched_barrier(0);
        if (t < 7) STAGE_((t + 1) & 1, t + 1);

        const _Float16* Ab = (const _Float16*)(smem + (t & 1) * 32768);
        const _Float16* Bb = Ab + 8192;  // halves

        f16x8 a0[4], b0[4], a1[4], b1[4];
#pragma unroll
        for (int i = 0; i < 4; ++i)
            a0[i] = *(const f16x8*)(Ab + (wr * 64 + i * 16 + am) * 64 + c0);
#pragma unroll
        for (int j = 0; j < 4; ++j)
            b0[j] = *(const f16x8*)(Bb + (wc * 64 + j * 16 + am) * 64 + c0);
        __builtin_amdgcn_sched_barrier(0);
#pragma unroll
        for (int i = 0; i < 4; ++i)
            a1[i] = *(const f16x8*)(Ab + (wr * 64 + i * 16 + am) * 64 + c1);
#pragma unroll
        for (int j = 0; j < 4; ++j)
            b1[j] = *(const f16x8*)(Bb + (wc * 64 + j * 16 + am) * 64 + c1);

        asm volatile("s_waitcnt lgkmcnt(8)" ::: "memory");
        __builtin_amdgcn_sched_barrier(0);
        __builtin_amdgcn_s_setprio(1);
#pragma unroll
        for (int i = 0; i < 4; ++i)
#pragma unroll
            for (int j = 0; j < 4; ++j)
                acc[i][j] = __builtin_amdgcn_mfma_f32_16x16x32_f16(
                    b0[j], a0[i], acc[i][j], 0, 0, 0);
        __builtin_amdgcn_s_setprio(0);
        asm volatile("s_waitcnt lgkmcnt(0)" ::: "memory");
        __builtin_amdgcn_sched_barrier(0);
        __builtin_amdgcn_s_setprio(1);
#pragma unroll
        for (int i = 0; i < 4; ++i)
#pragma unroll
            for (int j = 0; j < 4; ++j)
                acc[i][j] = __builtin_amdgcn_mfma_f32_16x16x32_f16(
                    b1[j], a1[i], acc[i][j], 0, 0, 0);
        __builtin_amdgcn_s_setprio(0);
    }
#undef STAGE_

    const float* bias = (gate == 0) ? bz : (gate == 1) ? bfv : bo;
    _Float16* outp = (gate == 0) ? zbuf : (gate == 1) ? fbuf : obuf;
    const int nq = (lane >> 4) * 4;
#pragma unroll
    for (int i = 0; i < 4; ++i) {
        const size_t gm = (size_t)(m0 + wr * 64 + i * 16 + am);
#pragma unroll
        for (int j = 0; j < 4; ++j) {
            const int gc = n0 + wc * 64 + j * 16 + nq;
            const float4 b4 = *(const float4*)(bias + gc);
            f32x4 v = acc[i][j];
            f16x4 h;
            if (gate == 0) {
                h[0] = (_Float16)tanh_(v[0] + b4.x);
                h[1] = (_Float16)tanh_(v[1] + b4.y);
                h[2] = (_Float16)tanh_(v[2] + b4.z);
                h[3] = (_Float16)tanh_(v[3] + b4.w);
            } else {
                h[0] = (_Float16)sigmoid_(v[0] + b4.x);
                h[1] = (_Float16)sigmoid_(v[1] + b4.y);
                h[2] = (_Float16)sigmoid_(v[2] + b4.z);
                h[3] = (_Float16)sigmoid_(v[3] + b4.w);
            }
            *(f16x4*)(outp + gm * DDIM + gc) = h;
        }
    }
}

// ---------------------------------------------------------------------------
// Scan pass 1 (R10 diagnosis: latency-bound at 0.5 TB/s, 10x below roofline;
// rolled loop exposes ~16 serial load latencies).  Fix: issue ALL 32 loads
// (16 z + 16 f) upfront into register arrays (full unroll, static indices),
// pay the HBM latency ONCE, then compute from registers.
// ---------------------------------------------------------------------------
__global__ __launch_bounds__(256) void scan_pass1(
    const _Float16* __restrict__ zbuf, const _Float16* __restrict__ fbuf,
    float* __restrict__ aggA, float* __restrict__ aggB) {
    const int idx = blockIdx.x * 256 + threadIdx.x;  // < B*NCHUNK*64 = 131072
    const int d4 = idx & 63;
    const int chunk = (idx >> 6) & (NCHUNK - 1);
    const int b = idx >> 14;

    const size_t row0 = (size_t)b * TDIM + (size_t)chunk * LCHUNK;
    const int2* zp = (const int2*)zbuf + row0 * 64 + d4;
    const int2* fp = (const int2*)fbuf + row0 * 64 + d4;

    int2 zr[LCHUNK], fr[LCHUNK];
#pragma unroll
    for (int i = 0; i < LCHUNK; ++i) {
        fr[i] = fp[(size_t)i * 64];
        zr[i] = zp[(size_t)i * 64];
    }

    float A[4], c[4];
#pragma unroll
    for (int e = 0; e < 4; ++e) { A[e] = 1.0f; c[e] = 0.0f; }

#pragma unroll
    for (int i = 0; i < LCHUNK; ++i) {
        const _Float16* fh = (const _Float16*)&fr[i];
        const _Float16* zh = (const _Float16*)&zr[i];
#pragma unroll
        for (int e = 0; e < 4; ++e) {
            const float f = (float)fh[e];
            const float z = (float)zh[e];
            A[e] *= f;
            c[e] = f * c[e] + (1.0f - f) * z;
        }
    }
    ((float4*)aggA)[idx] = make_float4(A[0], A[1], A[2], A[3]);
    ((float4*)aggB)[idx] = make_float4(c[0], c[1], c[2], c[3]);
}

// ---------------------------------------------------------------------------
// Carry scan across chunks: one thread per (b,d) = 2048 threads.
// Unroll-16 batched loads: 16 latency rounds instead of 32.
// ---------------------------------------------------------------------------
__global__ __launch_bounds__(256) void carry_scan(
    const float* __restrict__ aggA, const float* __restrict__ aggB,
    float* __restrict__ carry) {
    const int g = blockIdx.x * 256 + threadIdx.x;  // < B*D = 2048
    const int d = g & 255;
    const int b = g >> 8;
    const size_t base = (size_t)b * NCHUNK * 256 + d;

    float c = 0.0f;
    for (int ch0 = 0; ch0 < NCHUNK; ch0 += 16) {
        float A[16], Bv[16];
#pragma unroll
        for (int u = 0; u < 16; ++u) {
            const size_t p = base + (size_t)(ch0 + u) * 256;
            A[u] = aggA[p];
            Bv[u] = aggB[p];
        }
#pragma unroll
        for (int u = 0; u < 16; ++u) {
            const size_t p = base + (size_t)(ch0 + u) * 256;
            carry[p] = c;
            c = A[u] * c + Bv[u];
        }
    }
}

// ---------------------------------------------------------------------------
// Scan pass 2: same ILP fix -- carry + all 48 loads (z,f,o) issued upfront
// into registers, then compute + 16 float4 stores.
// ---------------------------------------------------------------------------
__global__ __launch_bounds__(256) void scan_pass2(
    const _Float16* __restrict__ zbuf, const _Float16* __restrict__ fbuf,
    const _Float16* __restrict__ obuf, const float* __restrict__ carry,
    float* __restrict__ out) {
    const int idx = blockIdx.x * 256 + threadIdx.x;  // < 131072
    const int d4 = idx & 63;
    const int chunk = (idx >> 6) & (NCHUNK - 1);
    const int b = idx >> 14;

    const size_t row0 = (size_t)b * TDIM + (size_t)chunk * LCHUNK;
    const int2* zp = (const int2*)zbuf + row0 * 64 + d4;
    const int2* fp = (const int2*)fbuf + row0 * 64 + d4;
    const int2* op = (const int2*)obuf + row0 * 64 + d4;
    float4* hp = (float4*)out + row0 * 64 + d4;

    const float4 c0 = ((const float4*)carry)[idx];

    int2 zr[LCHUNK], fr[LCHUNK], orr[LCHUNK];
#pragma unroll
    for (int i = 0; i < LCHUNK; ++i) {
        fr[i] = fp[(size_t)i * 64];
        zr[i] = zp[(size_t)i * 64];
        orr[i] = op[(size_t)i * 64];
    }

    float c[4];
    c[0] = c0.x; c[1] = c0.y; c[2] = c0.z; c[3] = c0.w;

#pragma unroll
    for (int i = 0; i < LCHUNK; ++i) {
        const _Float16* fh = (const _Float16*)&fr[i];
        const _Float16* zh = (const _Float16*)&zr[i];
        const _Float16* oh = (const _Float16*)&orr[i];
        float h[4];
#pragma unroll
        for (int e = 0; e < 4; ++e) {
            const float f = (float)fh[e];
            const float z = (float)zh[e];
            c[e] = f * c[e] + (1.0f - f) * z;
            h[e] = (float)oh[e] * c[e];
        }
        hp[(size_t)i * 64] = make_float4(h[0], h[1], h[2], h[3]);
    }
}

extern "C" void kernel_launch(void* const* d_in, const int* in_sizes, int n_in,
                              void* d_out, int out_size, void* d_ws,
                              size_t ws_size, hipStream_t stream) {
    const float* x = (const float*)d_in[0];
    const float* Wz = (const float*)d_in[1];
    const float* Wf = (const float*)d_in[2];
    const float* Wo = (const float*)d_in[3];
    const float* bz = (const float*)d_in[4];
    const float* bfv = (const float*)d_in[5];
    const float* bo = (const float*)d_in[6];
    float* out = (float*)d_out;

    // Workspace (bytes): xpad 16.78M | Wt 0.79M | z 16.78M | f 16.78M |
    // o 16.78M | aggA 2M | aggB 2M | carry 2M   -> ~74.7 MB
    char* p = (char*)d_ws;
    _Float16* xpad = (_Float16*)p;  p += (size_t)BDIM * (TDIM + 1) * DDIM * 2;
    _Float16* Wt = (_Float16*)p;    p += (size_t)3 * 256 * 512 * 2;
    _Float16* zbuf = (_Float16*)p;  p += (size_t)MDIM * DDIM * 2;
    _Float16* fbuf = (_Float16*)p;  p += (size_t)MDIM * DDIM * 2;
    _Float16* obuf = (_Float16*)p;  p += (size_t)MDIM * DDIM * 2;
    float* aggA = (float*)p;        p += (size_t)BDIM * NCHUNK * DDIM * 4;
    float* aggB = (float*)p;        p += (size_t)BDIM * NCHUNK * DDIM * 4;
    float* carry = (float*)p;

    prep<<<1536 + 1025 * BDIM, 256, 0, stream>>>(x, xpad, Wz, Wf, Wo, Wt);

    gates_mfma<<<MDIM / 128 * (DDIM / 128) * 3, 256, 0, stream>>>(
        xpad, Wt, bz, bfv, bo, zbuf, fbuf, obuf);

    scan_pass1<<<(BDIM * NCHUNK * 64) / 256, 256, 0, stream>>>(zbuf, fbuf,
                                                               aggA, aggB);
    carry_scan<<<(BDIM * DDIM) / 256, 256, 0, stream>>>(aggA, aggB, carry);
    scan_pass2<<<(BDIM * NCHUNK * 64) / 256, 256, 0, stream>>>(zbuf, fbuf,
                                                               obuf, carry, out);
}

// Round 12
// 152.544 us; speedup vs baseline: 1.2073x; 1.0587x over previous
//
#include <hip/hip_runtime.h>
#include <hip/hip_bf16.h>
#include <hip/hip_fp16.h>

// Problem constants (B=8, T=4096, Din=Dout=256, WINDOW=2)
#define BDIM 8
#define TDIM 4096
#define DDIM 256
#define MDIM (BDIM * TDIM)      // 32768
#define NCHUNK 256              // chunks along T for the parallel scan
#define LCHUNK (TDIM / NCHUNK)  // 16

typedef _Float16 f16x8 __attribute__((ext_vector_type(8)));
typedef _Float16 f16x4 __attribute__((ext_vector_type(4)));
typedef float f32x4 __attribute__((ext_vector_type(4)));

__device__ __forceinline__ float sigmoid_(float x) {
    return 1.0f / (1.0f + __expf(-x));
}
__device__ __forceinline__ float tanh_(float x) {
    return 2.0f / (1.0f + __expf(-2.0f * x)) - 1.0f;
}

#define GLOAD_LDS16(g, l)                                                    \
    __builtin_amdgcn_global_load_lds(                                        \
        (const __attribute__((address_space(1))) void*)(g),                  \
        (__attribute__((address_space(3))) void*)(l), 16, 0, 0)

// ---------------------------------------------------------------------------
// Fused prep: blocks [0,1536) convert W, blocks [1536,9736) convert x.
// ---------------------------------------------------------------------------
__global__ __launch_bounds__(256) void prep(
    const float* __restrict__ x, _Float16* __restrict__ xpad,
    const float* __restrict__ Wz, const float* __restrict__ Wf,
    const float* __restrict__ Wo, _Float16* __restrict__ Wt) {
    const int bx = blockIdx.x;
    if (bx < 1536) {  // convert_w: 1536*256 = 3*2*256*256 threads
        const int idx = bx * 256 + threadIdx.x;
        const int n = idx & 255;
        const int kin = (idx >> 8) & 255;
        const int w = (idx >> 16) & 1;
        const int g = idx >> 17;
        const float* W = (g == 0) ? Wz : (g == 1) ? Wf : Wo;
        const float v = W[(size_t)w * 65536 + (size_t)kin * 256 + n];
        Wt[((size_t)g * 256 + n) * 512 + w * 256 + kin] = (_Float16)v;
        return;
    }
    const int bxx = bx - 1536;        // 8200 blocks: 1025 per batch
    const int b = bxx / 1025;
    const int tb = bxx - b * 1025;
    const int tp = tb * 4 + (threadIdx.x >> 6);  // padded row 0..4096
    const int q = threadIdx.x & 63;
    if (tp > TDIM) return;
    float4 v = make_float4(0.f, 0.f, 0.f, 0.f);
    if (tp > 0)
        v = *(const float4*)(x + ((size_t)b * TDIM + tp - 1) * DDIM + q * 4);
    f16x4 h;
    h[0] = (_Float16)v.x; h[1] = (_Float16)v.y;
    h[2] = (_Float16)v.z; h[3] = (_Float16)v.w;
    *(f16x4*)(xpad + ((size_t)b * (TDIM + 1) + tp) * DDIM + q * 4) = h;
}

// ---------------------------------------------------------------------------
// MFMA GEMM, BK=64 two-phase K-tiles -- R7-verified config (K-loop
// untouched).  ONLY CHANGE: epilogue stores z/f/o in channel-group-major
// layout  buf[(b*64 + ch/4)*T + t][4ch]  (f16x4) so the fused scan kernel
// gets block-local, thread-contiguous chunk data.
// ---------------------------------------------------------------------------
__global__ __launch_bounds__(256, 2) void gates_mfma(
    const _Float16* __restrict__ xpad, const _Float16* __restrict__ Wt,
    const float* __restrict__ bz, const float* __restrict__ bfv,
    const float* __restrict__ bo,
    _Float16* __restrict__ zbuf, _Float16* __restrict__ fbuf,
    _Float16* __restrict__ obuf) {
    const int hw = blockIdx.x;
    const int logical = (hw & 7) * 192 + (hw >> 3);
    const int mblk = logical / 6;
    const int rem = logical - mblk * 6;   // (n,gate) innermost
    const int gate = rem % 3;
    const int nblk = rem / 3;
    const int m0 = mblk * 128;
    const int n0 = nblk * 128;

    const int tid = threadIdx.x;
    const int lane = tid & 63;
    const int wave = tid >> 6;
    const int wr = wave >> 1;
    const int wc = wave & 1;

    __shared__ __align__(16) char smem[65536];

    const int s = wave * 64 + lane;
    const int r1 = s >> 3;
    const int kc = (((s & 7) ^ ((s >> 3) & 7))) * 8;

    const int b = m0 >> 12;
    const int t0 = m0 & (TDIM - 1);

    const _Float16* srcA =
        xpad + ((size_t)b * (TDIM + 1) + t0 + r1) * DDIM + kc;
    const _Float16* srcB = Wt + ((size_t)gate * 256 + n0 + r1) * 512 + kc;

#define STAGE_(slot, kt)                                                     \
    {                                                                        \
        char* dA = smem + (slot) * 32768 + wave * 1024;                      \
        char* dB = smem + (slot) * 32768 + 16384 + wave * 1024;              \
        GLOAD_LDS16(srcA + (kt) * 64, dA);                                   \
        GLOAD_LDS16(srcA + (kt) * 64 + 32 * DDIM, dA + 4096);                \
        GLOAD_LDS16(srcA + (kt) * 64 + 64 * DDIM, dA + 8192);                \
        GLOAD_LDS16(srcA + (kt) * 64 + 96 * DDIM, dA + 12288);               \
        GLOAD_LDS16(srcB + (kt) * 64, dB);                                   \
        GLOAD_LDS16(srcB + (kt) * 64 + 32 * 512, dB + 4096);                 \
        GLOAD_LDS16(srcB + (kt) * 64 + 64 * 512, dB + 8192);                 \
        GLOAD_LDS16(srcB + (kt) * 64 + 96 * 512, dB + 12288);               \
    }

    f32x4 acc[4][4] = {};
    const int am = lane & 15;
    const int c0 = (((lane >> 4) ^ (lane & 7))) * 8;
    const int c1 = (((4 + (lane >> 4)) ^ (lane & 7))) * 8;

    STAGE_(0, 0);

#pragma unroll
    for (int t = 0; t < 8; ++t) {
        asm volatile("s_waitcnt vmcnt(0)" ::: "memory");
        __builtin_amdgcn_s_barrier();
        __builtin_amdgcn_sched_barrier(0);
        if (t < 7) STAGE_((t + 1) & 1, t + 1);

        const _Float16* Ab = (const _Float16*)(smem + (t & 1) * 32768);
        const _Float16* Bb = Ab + 8192;  // halves

        f16x8 a0[4], b0[4], a1[4], b1[4];
#pragma unroll
        for (int i = 0; i < 4; ++i)
            a0[i] = *(const f16x8*)(Ab + (wr * 64 + i * 16 + am) * 64 + c0);
#pragma unroll
        for (int j = 0; j < 4; ++j)
            b0[j] = *(const f16x8*)(Bb + (wc * 64 + j * 16 + am) * 64 + c0);
        __builtin_amdgcn_sched_barrier(0);
#pragma unroll
        for (int i = 0; i < 4; ++i)
            a1[i] = *(const f16x8*)(Ab + (wr * 64 + i * 16 + am) * 64 + c1);
#pragma unroll
        for (int j = 0; j < 4; ++j)
            b1[j] = *(const f16x8*)(Bb + (wc * 64 + j * 16 + am) * 64 + c1);

        asm volatile("s_waitcnt lgkmcnt(8)" ::: "memory");
        __builtin_amdgcn_sched_barrier(0);
        __builtin_amdgcn_s_setprio(1);
#pragma unroll
        for (int i = 0; i < 4; ++i)
#pragma unroll
            for (int j = 0; j < 4; ++j)
                acc[i][j] = __builtin_amdgcn_mfma_f32_16x16x32_f16(
                    b0[j], a0[i], acc[i][j], 0, 0, 0);
        __builtin_amdgcn_s_setprio(0);
        asm volatile("s_waitcnt lgkmcnt(0)" ::: "memory");
        __builtin_amdgcn_sched_barrier(0);
        __builtin_amdgcn_s_setprio(1);
#pragma unroll
        for (int i = 0; i < 4; ++i)
#pragma unroll
            for (int j = 0; j < 4; ++j)
                acc[i][j] = __builtin_amdgcn_mfma_f32_16x16x32_f16(
                    b1[j], a1[i], acc[i][j], 0, 0, 0);
        __builtin_amdgcn_s_setprio(0);
    }
#undef STAGE_

    const float* bias = (gate == 0) ? bz : (gate == 1) ? bfv : bo;
    _Float16* outp = (gate == 0) ? zbuf : (gate == 1) ? fbuf : obuf;
    const int nq = (lane >> 4) * 4;
    const int tl0 = t0 + wr * 64;  // local t of frag row am at i=0
#pragma unroll
    for (int i = 0; i < 4; ++i) {
        const int tloc = tl0 + i * 16 + am;
#pragma unroll
        for (int j = 0; j < 4; ++j) {
            const int gc = n0 + wc * 64 + j * 16 + nq;  // gc % 4 == 0
            const float4 b4 = *(const float4*)(bias + gc);
            f32x4 v = acc[i][j];
            f16x4 h;
            if (gate == 0) {
                h[0] = (_Float16)tanh_(v[0] + b4.x);
                h[1] = (_Float16)tanh_(v[1] + b4.y);
                h[2] = (_Float16)tanh_(v[2] + b4.z);
                h[3] = (_Float16)tanh_(v[3] + b4.w);
            } else {
                h[0] = (_Float16)sigmoid_(v[0] + b4.x);
                h[1] = (_Float16)sigmoid_(v[1] + b4.y);
                h[2] = (_Float16)sigmoid_(v[2] + b4.z);
                h[3] = (_Float16)sigmoid_(v[3] + b4.w);
            }
            // channel-group-major: [(b*64 + gc/4) * T + tloc] * 4 halves
            *(f16x4*)(outp +
                      (((size_t)(b * 64 + (gc >> 2))) * TDIM + tloc) * 4) = h;
        }
    }
}

// ---------------------------------------------------------------------------
// Fused scan: ONE kernel, block-local (no cross-block sync; replaces
// pass1 + carry_scan + pass2).  Block = (b, d4-group): 8 x 64 = 512 blocks.
// blockIdx & 7 = b  ==> all 64 blocks of a batch on one XCD (out-line
// write-merge + L2 locality).  Thread t owns chunk t (16 steps, 4 ch):
//  1. all 48 loads (z,f,o; 128 B contiguous per array per thread) upfront
//  2. per-chunk affine aggregate (A, B): c_out = A*c_in + B
//  3. block-exclusive scan of affines: shfl_up intra-wave + LDS cross-wave
//     (composition (A2,B2)o(A1,B1) = (A2*A1, A2*B1+B2))
//  4. replay chunk from registers with carry = B_excl; write out [B,T,D].
// ---------------------------------------------------------------------------
__global__ __launch_bounds__(256) void scan_fused(
    const _Float16* __restrict__ zbuf, const _Float16* __restrict__ fbuf,
    const _Float16* __restrict__ obuf, float* __restrict__ out) {
    const int b = blockIdx.x & 7;
    const int d4 = blockIdx.x >> 3;   // 0..63
    const int t = threadIdx.x;        // chunk id 0..255
    const int lane = t & 63;
    const int wv = t >> 6;            // wave 0..3

    const size_t cb = ((size_t)(b * 64 + d4)) * TDIM;  // int2 units
    const int2* zp = (const int2*)zbuf + cb;
    const int2* fp = (const int2*)fbuf + cb;
    const int2* op = (const int2*)obuf + cb;

    // 1) all loads upfront (ILP; R11-verified pattern)
    int2 zr[LCHUNK], fr[LCHUNK], orr[LCHUNK];
#pragma unroll
    for (int i = 0; i < LCHUNK; ++i) {
        zr[i] = zp[t * LCHUNK + i];
        fr[i] = fp[t * LCHUNK + i];
        orr[i] = op[t * LCHUNK + i];
    }

    // 2) chunk-local affine aggregate
    float A[4], Bv[4];
#pragma unroll
    for (int e = 0; e < 4; ++e) { A[e] = 1.0f; Bv[e] = 0.0f; }
#pragma unroll
    for (int i = 0; i < LCHUNK; ++i) {
        const _Float16* fh = (const _Float16*)&fr[i];
        const _Float16* zh = (const _Float16*)&zr[i];
#pragma unroll
        for (int e = 0; e < 4; ++e) {
            const float f = (float)fh[e];
            const float z = (float)zh[e];
            A[e] *= f;
            Bv[e] = f * Bv[e] + (1.0f - f) * z;
        }
    }

    // 3a) intra-wave inclusive scan (lane = chunk order within wave)
    float Ai[4], Bi[4];
#pragma unroll
    for (int e = 0; e < 4; ++e) { Ai[e] = A[e]; Bi[e] = Bv[e]; }
#pragma unroll
    for (int off = 1; off < 64; off <<= 1) {
        float Au[4], Bu[4];
#pragma unroll
        for (int e = 0; e < 4; ++e) {
            Au[e] = __shfl_up(Ai[e], off);
            Bu[e] = __shfl_up(Bi[e], off);
        }
        if (lane >= off) {
#pragma unroll
            for (int e = 0; e < 4; ++e) {
                Bi[e] = Ai[e] * Bu[e] + Bi[e];  // earlier (Au,Bu) first
                Ai[e] = Ai[e] * Au[e];
            }
        }
    }

    // 3b) cross-wave: wave totals -> LDS; exclusive wave-prefix per thread
    __shared__ float sA[4][4], sB[4][4];
    if (lane == 63) {
#pragma unroll
        for (int e = 0; e < 4; ++e) { sA[wv][e] = Ai[e]; sB[wv][e] = Bi[e]; }
    }
    __syncthreads();
    float Ap[4], Bp[4];
#pragma unroll
    for (int e = 0; e < 4; ++e) { Ap[e] = 1.0f; Bp[e] = 0.0f; }
#pragma unroll
    for (int w = 0; w < 3; ++w) {
        if (w < wv) {
#pragma unroll
            for (int e = 0; e < 4; ++e) {
                Bp[e] = sA[w][e] * Bp[e] + sB[w][e];  // wave w applied after
                Ap[e] = sA[w][e] * Ap[e];
            }
        }
    }

    // 3c) intra-wave exclusive from inclusive (shift by 1)
    float Ae[4], Be[4];
#pragma unroll
    for (int e = 0; e < 4; ++e) {
        Ae[e] = __shfl_up(Ai[e], 1);
        Be[e] = __shfl_up(Bi[e], 1);
    }
    if (lane == 0) {
#pragma unroll
        for (int e = 0; e < 4; ++e) { Ae[e] = 1.0f; Be[e] = 0.0f; }
    }

    // carry into chunk t = (intra_excl o wave_prefix)(c0=0) = Ae*Bp + Be
    float c[4];
#pragma unroll
    for (int e = 0; e < 4; ++e) c[e] = Ae[e] * Bp[e] + Be[e];

    // 4) replay with true carry; h = o*c -> out [B,T,D] fp32
    float4* hp = (float4*)out + ((size_t)b * TDIM) * 64 + d4;
#pragma unroll
    for (int i = 0; i < LCHUNK; ++i) {
        const _Float16* fh = (const _Float16*)&fr[i];
        const _Float16* zh = (const _Float16*)&zr[i];
        const _Float16* oh = (const _Float16*)&orr[i];
        float h[4];
#pragma unroll
        for (int e = 0; e < 4; ++e) {
            const float f = (float)fh[e];
            const float z = (float)zh[e];
            c[e] = f * c[e] + (1.0f - f) * z;
            h[e] = (float)oh[e] * c[e];
        }
        hp[(size_t)(t * LCHUNK + i) * 64] = make_float4(h[0], h[1], h[2], h[3]);
    }
}

extern "C" void kernel_launch(void* const* d_in, const int* in_sizes, int n_in,
                              void* d_out, int out_size, void* d_ws,
                              size_t ws_size, hipStream_t stream) {
    const float* x = (const float*)d_in[0];
    const float* Wz = (const float*)d_in[1];
    const float* Wf = (const float*)d_in[2];
    const float* Wo = (const float*)d_in[3];
    const float* bz = (const float*)d_in[4];
    const float* bfv = (const float*)d_in[5];
    const float* bo = (const float*)d_in[6];
    float* out = (float*)d_out;

    // Workspace (bytes): xpad 16.78M | Wt 0.79M | z 16.78M | f 16.78M |
    // o 16.78M  (z/f/o in channel-group-major layout)
    char* p = (char*)d_ws;
    _Float16* xpad = (_Float16*)p;  p += (size_t)BDIM * (TDIM + 1) * DDIM * 2;
    _Float16* Wt = (_Float16*)p;    p += (size_t)3 * 256 * 512 * 2;
    _Float16* zbuf = (_Float16*)p;  p += (size_t)MDIM * DDIM * 2;
    _Float16* fbuf = (_Float16*)p;  p += (size_t)MDIM * DDIM * 2;
    _Float16* obuf = (_Float16*)p;  p += (size_t)MDIM * DDIM * 2;

    prep<<<1536 + 1025 * BDIM, 256, 0, stream>>>(x, xpad, Wz, Wf, Wo, Wt);

    gates_mfma<<<MDIM / 128 * (DDIM / 128) * 3, 256, 0, stream>>>(
        xpad, Wt, bz, bfv, bo, zbuf, fbuf, obuf);

    scan_fused<<<BDIM * 64, 256, 0, stream>>>(zbuf, fbuf, obuf, out);
}